// Round 1
// baseline (125.681 us; speedup 1.0000x reference)
//
#include <hip/hip_runtime.h>

// DGI forward on MI355X.
// Pipeline: K0 (comm map) ; K1 (F = f16[seq@W], tile-transposed) ;
// K2 (Pp = adj@F split-K MFMA partials, adj scaled 2^12 into f16) ;
// K2R (h = relu(sum(Pp)/2^12 + b)) ; K3a (community sums S) ;
// K3b (c=sigmoid(S/1024), cw=c@Wb^T) ; K5 (per-node bilinear score -> out).

#define NN    8192
#define NCOLS 256
#define ASCALE 4096.0f
#define AINV  (1.0f/4096.0f)

typedef _Float16 half8 __attribute__((ext_vector_type(8)));
typedef float    f32x4 __attribute__((ext_vector_type(4)));

__device__ __forceinline__ void gload16(const void* g, void* l) {
  __builtin_amdgcn_global_load_lds(
      (const __attribute__((address_space(1))) char*)g,
      (__attribute__((address_space(3))) char*)l, 16, 0, 0);
}

// ---------------- K0: node->community inverse map, zero S ----------------
__global__ void k0_init(const int* __restrict__ cc, int* __restrict__ node_comm,
                        float* __restrict__ S) {
  int i = blockIdx.x * 256 + threadIdx.x;     // 0..8191
  if (i < 1024) S[i] = 0.0f;
  node_comm[cc[i]] = i >> 10;                 // CS = 1024
}

// ---------------- K1: F tiles = f16(seq@W), layout [tile32][col256][k32] ----------------
__global__ __launch_bounds__(256) void k1_fts(const float* __restrict__ seq1,
                                              const float* __restrict__ seq2,
                                              const float* __restrict__ W,
                                              _Float16* __restrict__ F) {
  __shared__ char lds[65536];
  _Float16* Wt  = (_Float16*)lds;             // 32KB: W^T f16, swizzled [128 col][128 d]
  float*    sSeq = (float*)(lds + 32768);     // 32KB: seq tile f32 swizzled [64][128]; reused as out image
  const int tid = threadIdx.x;
  const int lane = tid & 63;
  const int w = tid >> 6;                     // 4 waves
  const int l15 = lane & 15;
  const int g = lane >> 4;
  const int m0 = blockIdx.x * 64;

  // Build W^T f16 swizzled: byte(h,d) = (h*256 + d*2) ^ ((h&7)<<4)
  for (int it = 0; it < 64; ++it) {
    int idx = it * 256 + tid;                 // W row-major [d][h]
    int d = idx >> 7, hc = idx & 127;
    int byte = (hc * 256 + d * 2) ^ ((hc & 7) << 4);
    *(_Float16*)(lds + byte) = (_Float16)W[idx];
  }

  const float* seqp[2] = {seq1, seq2};
  const int srow = tid >> 5;                  // 0..7
  const int sck = tid & 31;                   // 16B chunk in 512B row

  for (int s = 0; s < 2; ++s) {
    __syncthreads();                          // prev copy done / Wt built
    const float* sp = seqp[s];
#pragma unroll
    for (int i = 0; i < 8; ++i) {             // stage 64x128 f32, swizzled src
      int row = i * 8 + srow;
      gload16(sp + (size_t)(m0 + row) * 128 + ((sck ^ (row & 7)) << 2),
              (char*)sSeq + i * 4096 + w * 1024);
    }
    asm volatile("s_waitcnt vmcnt(0)" ::: "memory");
    __syncthreads();

    f32x4 acc[4][2] = {};
    const float4* S4 = (const float4*)sSeq;
    const float4* W4 = (const float4*)Wt;
#pragma unroll
    for (int kk = 0; kk < 4; ++kk) {
      half8 bf[2];
#pragma unroll
      for (int nf = 0; nf < 2; ++nf) {
        int col = w * 32 + nf * 16 + l15;
        float4 bv = W4[(col * 16 + kk * 4 + g) ^ (col & 7)];
        bf[nf] = *(const half8*)&bv;
      }
#pragma unroll
      for (int mf = 0; mf < 4; ++mf) {
        int row = mf * 16 + l15;
        int bidx = row * 32 + kk * 8 + g * 2;
        float4 u = S4[bidx ^ (row & 7)];
        float4 v = S4[(bidx + 1) ^ (row & 7)];
        half8 af;
#pragma unroll
        for (int j = 0; j < 4; ++j) af[j] = (_Float16)(((const float*)&u)[j]);
#pragma unroll
        for (int j = 0; j < 4; ++j) af[4 + j] = (_Float16)(((const float*)&v)[j]);
#pragma unroll
        for (int nf = 0; nf < 2; ++nf)
          acc[mf][nf] = __builtin_amdgcn_mfma_f32_16x16x32_f16(af, bf[nf], acc[mf][nf], 0, 0, 0);
      }
    }
    __syncthreads();                          // done reading sSeq
    // Emit image [kt][c][k] (halves) into sSeq region
    _Float16* img = (_Float16*)sSeq;
#pragma unroll
    for (int mf = 0; mf < 4; ++mf)
#pragma unroll
      for (int nf = 0; nf < 2; ++nf) {
        int col = w * 32 + nf * 16 + l15;
#pragma unroll
        for (int j = 0; j < 4; ++j) {
          int kl = mf * 16 + g * 4 + j;       // local node 0..63 (C/D: row=(l>>4)*4+j)
          img[(kl >> 5) * 4096 + col * 32 + (kl & 31)] = (_Float16)acc[mf][nf][j];
        }
      }
    __syncthreads();
    const float4* src4 = (const float4*)sSeq;
#pragma unroll
    for (int i = 0; i < 4; ++i) {             // 16KB -> global, linear
      int e = i * 256 + tid;
      int kt = e >> 9, off = e & 511;
      ((float4*)(F + (size_t)(2 * blockIdx.x + kt) * 8192))[s * 512 + off] = src4[e];
    }
  }
}

// ---------------- K2: split-K GEMM partials Pp[ks][m][n] = (adj*2^12)@F ----------------
__global__ __launch_bounds__(512) void k2_gemm(const float* __restrict__ adj,
                                               const _Float16* __restrict__ F,
                                               float* __restrict__ Pp) {
  __shared__ float    sA0[4096];              // 16KB: [128 row][32 k] f32, XOR-swizzled
  __shared__ float    sA1[4096];
  __shared__ _Float16 sB0[8192];              // 16KB: [256 col][32 k] f16, linear
  __shared__ _Float16 sB1[8192];
  const int tid = threadIdx.x;                // 512
  const int lane = tid & 63;
  const int w = tid >> 6;                     // 8 waves
  const int l15 = lane & 15;
  const int g = lane >> 4;
  const int row0 = blockIdx.x * 128;          // M tile
  const int ks = blockIdx.y;                  // 0..3 split-K
  const int kcol0 = ks * 2048;

  const int ar0 = tid >> 3;                   // staging row (instr0), chunk = tid&7
  const int ac = tid & 7;
  const float* asrc0 = adj + (size_t)(row0 + ar0) * NN + kcol0 + ((ac ^ (ar0 & 7)) << 2);
  const float* asrc1 = adj + (size_t)(row0 + ar0 + 64) * NN + kcol0 + ((ac ^ (ar0 & 7)) << 2);
  const char*  bsrc  = (const char*)F + (size_t)(ks * 64) * 16384 + (size_t)tid * 16;

  auto stage = [&](float* sA, _Float16* sB, int t) {
    gload16(asrc0 + t * 32, (char*)sA + w * 1024);
    gload16(asrc1 + t * 32, (char*)sA + 8192 + w * 1024);
    const char* bs = bsrc + (size_t)t * 16384;
    gload16(bs,        (char*)sB + w * 1024);
    gload16(bs + 8192, (char*)sB + 8192 + w * 1024);
  };

  const int wm = w >> 2, wn = w & 3;          // 2x4 wave grid, 64x64 per wave
  f32x4 acc[4][4] = {};

  auto compute = [&](const float* sA, const _Float16* sB) {
    const float4* A4 = (const float4*)sA;
    const float4* B4 = (const float4*)sB;
    half8 bf[4];
#pragma unroll
    for (int nf = 0; nf < 4; ++nf) {
      int col = wn * 64 + nf * 16 + l15;
      float4 bv = B4[col * 4 + g];            // dense 1KB span per frag: conflict-free
      bf[nf] = *(const half8*)&bv;
    }
#pragma unroll
    for (int mf = 0; mf < 4; ++mf) {
      int row = wm * 64 + mf * 16 + l15;
      int bidx = row * 8 + g * 2;
      float4 u = A4[bidx ^ (row & 7)];
      float4 v = A4[(bidx + 1) ^ (row & 7)];
      half8 af;
#pragma unroll
      for (int j = 0; j < 4; ++j) af[j] = (_Float16)(((const float*)&u)[j] * ASCALE);
#pragma unroll
      for (int j = 0; j < 4; ++j) af[4 + j] = (_Float16)(((const float*)&v)[j] * ASCALE);
#pragma unroll
      for (int nf = 0; nf < 4; ++nf)
        acc[mf][nf] = __builtin_amdgcn_mfma_f32_16x16x32_f16(af, bf[nf], acc[mf][nf], 0, 0, 0);
    }
  };

  stage(sA0, sB0, 0);
  asm volatile("s_waitcnt vmcnt(0)" ::: "memory");
  __syncthreads();
  for (int t = 0; t < 64; t += 2) {           // 2048 / BK32 = 64 steps
    stage(sA1, sB1, t + 1);
    compute(sA0, sB0);
    asm volatile("s_waitcnt vmcnt(0)" ::: "memory");
    __syncthreads();
    if (t + 2 < 64) stage(sA0, sB0, t + 2);
    compute(sA1, sB1);
    asm volatile("s_waitcnt vmcnt(0)" ::: "memory");
    __syncthreads();
  }

#pragma unroll
  for (int mf = 0; mf < 4; ++mf)
#pragma unroll
    for (int nf = 0; nf < 4; ++nf) {
      int col = wn * 64 + nf * 16 + l15;
#pragma unroll
      for (int j = 0; j < 4; ++j) {
        int row = row0 + wm * 64 + mf * 16 + g * 4 + j;
        Pp[((size_t)ks * NN + row) * NCOLS + col] = acc[mf][nf][j];
      }
    }
}

// ---------------- K2R: h = relu(sum_ks(Pp)/2^12 + b) ----------------
__global__ void k2r_reduce(const float* __restrict__ Pp, const float* __restrict__ b,
                           float* __restrict__ h) {
  int gid = blockIdx.x * 256 + threadIdx.x;   // 0..524287 float4s
  size_t base = (size_t)gid * 4;
  float4 p0 = *(const float4*)(Pp + base);
  float4 p1 = *(const float4*)(Pp + base + 2097152);
  float4 p2 = *(const float4*)(Pp + base + 4194304);
  float4 p3 = *(const float4*)(Pp + base + 6291456);
  int n0 = (int)(base & 255) & 127;
  float4 r;
  r.x = fmaxf((p0.x + p1.x + p2.x + p3.x) * AINV + b[n0],     0.f);
  r.y = fmaxf((p0.y + p1.y + p2.y + p3.y) * AINV + b[n0 + 1], 0.f);
  r.z = fmaxf((p0.z + p1.z + p2.z + p3.z) * AINV + b[n0 + 2], 0.f);
  r.w = fmaxf((p0.w + p1.w + p2.w + p3.w) * AINV + b[n0 + 3], 0.f);
  *(float4*)(h + base) = r;
}

// ---------------- K3a: community sums of h1 ----------------
__global__ __launch_bounds__(128) void k3a_csum(const float* __restrict__ h,
                                                const int* __restrict__ node_comm,
                                                float* __restrict__ S) {
  int hh = threadIdx.x;
  int n0 = blockIdx.x * 32;
  float a0=0,a1=0,a2=0,a3=0,a4=0,a5=0,a6=0,a7=0;
  for (int i = 0; i < 32; ++i) {
    int node = n0 + i;
    int c = node_comm[node];
    float v = h[(size_t)node * 256 + hh];     // h already relu'd; cols 0..127 = seq1
    a0 += (c == 0) ? v : 0.f;  a1 += (c == 1) ? v : 0.f;
    a2 += (c == 2) ? v : 0.f;  a3 += (c == 3) ? v : 0.f;
    a4 += (c == 4) ? v : 0.f;  a5 += (c == 5) ? v : 0.f;
    a6 += (c == 6) ? v : 0.f;  a7 += (c == 7) ? v : 0.f;
  }
  if (a0 != 0.f) atomicAdd(&S[0 * 128 + hh], a0);
  if (a1 != 0.f) atomicAdd(&S[1 * 128 + hh], a1);
  if (a2 != 0.f) atomicAdd(&S[2 * 128 + hh], a2);
  if (a3 != 0.f) atomicAdd(&S[3 * 128 + hh], a3);
  if (a4 != 0.f) atomicAdd(&S[4 * 128 + hh], a4);
  if (a5 != 0.f) atomicAdd(&S[5 * 128 + hh], a5);
  if (a6 != 0.f) atomicAdd(&S[6 * 128 + hh], a6);
  if (a7 != 0.f) atomicAdd(&S[7 * 128 + hh], a7);
}

// ---------------- K3b: c = sigmoid(S/1024); cw = c @ Wb^T ----------------
__global__ __launch_bounds__(128) void k3b_cw(const float* __restrict__ S,
                                              const float* __restrict__ Wb,
                                              float* __restrict__ cw) {
  __shared__ float sc[128];
  int ci = blockIdx.x;                        // 0..7
  int hh = threadIdx.x;
  float m = S[ci * 128 + hh] * (1.0f / 1024.0f);
  sc[hh] = 1.0f / (1.0f + __expf(-m));
  __syncthreads();
  const float4* wr = (const float4*)(Wb + (size_t)hh * 128);
  float acc = 0.f;
#pragma unroll 8
  for (int k4 = 0; k4 < 32; ++k4) {
    float4 wv = wr[k4];
    acc += wv.x * sc[k4 * 4 + 0] + wv.y * sc[k4 * 4 + 1]
         + wv.z * sc[k4 * 4 + 2] + wv.w * sc[k4 * 4 + 3];
  }
  cw[ci * 128 + hh] = acc;
}

// ---------------- K5: per-node bilinear scores -> out ----------------
__global__ __launch_bounds__(256) void k5_score(const float* __restrict__ h,
                                                const int* __restrict__ node_comm,
                                                const float* __restrict__ cw,
                                                const float* __restrict__ bbp,
                                                float* __restrict__ out) {
  int tid = threadIdx.x;
  int q = tid & 15, nl = tid >> 4;
  int node = blockIdx.x * 16 + nl;
  int c = node_comm[node];
  const float* hr = h + (size_t)node * 256;
  const float* cr = cw + c * 128;
  float4 c0 = *(const float4*)(cr + q * 8);
  float4 c1 = *(const float4*)(cr + q * 8 + 4);
  float4 a0 = *(const float4*)(hr + q * 8);
  float4 a1 = *(const float4*)(hr + q * 8 + 4);
  float p1 = a0.x*c0.x + a0.y*c0.y + a0.z*c0.z + a0.w*c0.w
           + a1.x*c1.x + a1.y*c1.y + a1.z*c1.z + a1.w*c1.w;
  float4 b0 = *(const float4*)(hr + 128 + q * 8);
  float4 b1 = *(const float4*)(hr + 128 + q * 8 + 4);
  float p2 = b0.x*c0.x + b0.y*c0.y + b0.z*c0.z + b0.w*c0.w
           + b1.x*c1.x + b1.y*c1.y + b1.z*c1.z + b1.w*c1.w;
#pragma unroll
  for (int m = 8; m >= 1; m >>= 1) {
    p1 += __shfl_xor(p1, m, 64);
    p2 += __shfl_xor(p2, m, 64);
  }
  if (q == 0) {
    float bb = bbp[0];
    out[node] = p1 + bb;
    out[8192 + node] = p2 + bb;
  }
}

extern "C" void kernel_launch(void* const* d_in, const int* in_sizes, int n_in,
                              void* d_out, int out_size, void* d_ws, size_t ws_size,
                              hipStream_t stream) {
  (void)in_sizes; (void)n_in; (void)out_size; (void)ws_size;
  const float* seq1 = (const float*)d_in[0];
  const float* seq2 = (const float*)d_in[1];
  const float* adj  = (const float*)d_in[2];
  const int*   cc   = (const int*)d_in[3];
  const float* W    = (const float*)d_in[4];
  const float* b    = (const float*)d_in[5];
  const float* Wb   = (const float*)d_in[6];
  const float* bb   = (const float*)d_in[7];
  float* out = (float*)d_out;

  char* ws = (char*)d_ws;
  _Float16* F   = (_Float16*)(ws);                         // 4 MB
  float* h      = (float*)(ws + (4u << 20));               // 8 MB
  float* Pp     = (float*)(ws + (12u << 20));              // 32 MB
  float* S      = (float*)(ws + (44u << 20));              // 4 KB
  float* cw     = (float*)(ws + (44u << 20) + 4096);       // 4 KB
  int* node_comm = (int*)(ws + (44u << 20) + 8192);        // 32 KB

  k0_init<<<dim3(32), dim3(256), 0, stream>>>(cc, node_comm, S);
  k1_fts<<<dim3(128), dim3(256), 0, stream>>>(seq1, seq2, W, F);
  k2_gemm<<<dim3(64, 4), dim3(512), 0, stream>>>(adj, F, Pp);
  k2r_reduce<<<dim3(2048), dim3(256), 0, stream>>>(Pp, b, h);
  k3a_csum<<<dim3(256), dim3(128), 0, stream>>>(h, node_comm, S);
  k3b_cw<<<dim3(8), dim3(128), 0, stream>>>(S, Wb, cw);
  k5_score<<<dim3(512), dim3(256), 0, stream>>>(h, node_comm, cw, bb, out);
}